// Round 20
// baseline (82.163 us; speedup 1.0000x reference)
//
#include <hip/hip_runtime.h>

#define B_SZ 2
#define T_SZ 2048
#define C_SZ 1024
#define K_SZ 1024
#define QKV_LD 3072
#define H_CNT 16
#define D_SZ 64
#define WIN 512

typedef __bf16 bf16_t;
typedef bf16_t bf16x8 __attribute__((ext_vector_type(8)));
typedef bf16_t bf16x4 __attribute__((ext_vector_type(4)));
typedef float f32x4 __attribute__((ext_vector_type(4)));
typedef unsigned int u32;

__device__ __forceinline__ f32x4 mfma16(bf16x8 a, bf16x8 b, f32x4 c) {
  return __builtin_amdgcn_mfma_f32_16x16x32_bf16(a, b, c, 0, 0, 0);
}

__device__ __forceinline__ void gload_lds16(const void* gsrc, void* ldst) {
  auto g = (__attribute__((address_space(1))) void*)(unsigned long long)gsrc;
  auto l = (__attribute__((address_space(3))) void*)(unsigned int)(unsigned long long)ldst;
  __builtin_amdgcn_global_load_lds(g, l, 16, 0, 0);
}

// ---------------- prep: weight transpose+convert (z<4) | x convert (z==4)
__global__ __launch_bounds__(256) void prep(
    const float* __restrict__ x, bf16_t* __restrict__ xb,
    const float* __restrict__ W0, const float* __restrict__ W1,
    const float* __restrict__ W2, const float* __restrict__ W3,
    bf16_t* __restrict__ T0, bf16_t* __restrict__ T1,
    bf16_t* __restrict__ T2, bf16_t* __restrict__ T3) {
  if (blockIdx.z == 4) {
    const int base = (blockIdx.y * 32 + blockIdx.x) * 256 + threadIdx.x;
#pragma unroll
    for (int j = 0; j < 4; ++j) {
      const int idx = base + j * 262144;
      const float4 v = ((const float4*)x)[idx];
      bf16x4 r;
      r[0] = (bf16_t)v.x; r[1] = (bf16_t)v.y; r[2] = (bf16_t)v.z; r[3] = (bf16_t)v.w;
      ((bf16x4*)xb)[idx] = r;
    }
    return;
  }
  __shared__ float tile[32][33];
  const float* W = blockIdx.z == 0 ? W0 : blockIdx.z == 1 ? W1 : blockIdx.z == 2 ? W2 : W3;
  bf16_t* Tt = blockIdx.z == 0 ? T0 : blockIdx.z == 1 ? T1 : blockIdx.z == 2 ? T2 : T3;
  const int tx = threadIdx.x & 31, ty = threadIdx.x >> 5;
  const int r0 = blockIdx.y * 32, c0 = blockIdx.x * 32;
#pragma unroll
  for (int i = 0; i < 4; ++i)
    tile[ty + i * 8][tx] = W[(size_t)(r0 + ty + i * 8) * C_SZ + c0 + tx];
  __syncthreads();
#pragma unroll
  for (int i = 0; i < 4; ++i)
    Tt[(size_t)(c0 + ty + i * 8) * C_SZ + r0 + tx] = (bf16_t)tile[tx][ty + i * 8];
}

// ---------------- 256x192 GEMM, BK=64, 16 waves 4Mx4N (wave tile 64x48),
// 1024 thr -> 4 waves/SIMD intra-block TLP under thin sync: single entry
// barrier/tile, B triple-buffered depth-2 counted vmcnt, full unroll.
// acc 48 VGPR/wave -> fits 128-VGPR cap for 4 waves/SIMD.
#define GM_NT 16  // K / 64

__global__ __launch_bounds__(1024, 4) void gemm256(
    const bf16_t* __restrict__ A, const bf16_t* __restrict__ Bt,
    bf16_t* __restrict__ C, bf16_t* __restrict__ Vt) {
  __shared__ __align__(16) bf16_t As[2][256 * 64];
  __shared__ __align__(16) bf16_t Bs[3][192 * 64];
  const int wg = blockIdx.x + 16 * blockIdx.y;
  const int swz = (wg & 7) * 32 + (wg >> 3);
  const int bx = swz & 15, by = swz >> 4;
  const int m0 = by * 256, n0 = bx * 192;
  const int tid = threadIdx.x, w = tid >> 6, lane = tid & 63;
  const int wr = w >> 2, wc = w & 3;  // 4M x 4N
  const int g = lane >> 4, l15 = lane & 15, sw = l15 & 7;
  const int srow = lane >> 3, sj = lane & 7;

  f32x4 acc[4][3] = {};

  // A: 256 rows; wave w stages rows w*16 .. w*16+15 (2 gloads)
  auto stageA = [&](int buf, int k0) {
#pragma unroll
    for (int q8 = 0; q8 < 2; ++q8) {
      const int rg = w * 16 + q8 * 8;
      gload_lds16(A + (size_t)(m0 + rg + srow) * K_SZ + k0 + ((sj ^ srow) << 3),
                  &As[buf][rg * 64]);
    }
  };
  // B: 192 rows; waves 0..11 stage rows w*16 .. w*16+15 (2 gloads each)
  auto stageB = [&](int buf, int k0) {
#pragma unroll
    for (int q8 = 0; q8 < 2; ++q8) {
      const int rg = w * 16 + q8 * 8;
      gload_lds16(Bt + (size_t)(n0 + rg + srow) * K_SZ + k0 + ((sj ^ srow) << 3),
                  &Bs[buf][rg * 64]);
    }
  };

  // prologue (per-wave issue order: B(0), A(0), B(1))
  if (w < 12) stageB(0, 0);
  stageA(0, 0);
  if (w < 12) stageB(1, 64);

#define LDAF(MF, KK) \
  (*(const bf16x8*)&As[buf][(wr * 64 + (MF) * 16 + l15) * 64 + \
                            ((((KK) << 2) | g) ^ sw) * 8])
#define LDBF(NF, KK) \
  (*(const bf16x8*)&Bs[bB][(wc * 48 + (NF) * 16 + l15) * 64 + \
                           ((((KK) << 2) | g) ^ sw) * 8])
#define MROW(MF, AF)                              \
  acc[(MF)][0] = mfma16(AF, b0, acc[(MF)][0]);    \
  acc[(MF)][1] = mfma16(AF, b1, acc[(MF)][1]);    \
  acc[(MF)][2] = mfma16(AF, b2, acc[(MF)][2]);

#pragma unroll
  for (int t = 0; t < GM_NT; ++t) {
    const int buf = t & 1, nb = buf ^ 1;
    const int bB = t % 3;  // compile-time after full unroll
    const int k1 = (t + 1) * 64;
    // entry: drain B(t)+A(t); keep B(t+1)'s 2 loads in flight (w<12)
    if (t < GM_NT - 1) {
      if (w < 12) {
        asm volatile("s_waitcnt vmcnt(2)" ::: "memory");
      } else {
        asm volatile("s_waitcnt vmcnt(0)" ::: "memory");
      }
    } else {
      asm volatile("s_waitcnt vmcnt(0)" ::: "memory");
    }
    __builtin_amdgcn_s_barrier();

    {  // P0: kk0 (12 MFMA) + stage A(t+1)
      bf16x8 a0 = LDAF(0, 0), a1 = LDAF(1, 0), a2 = LDAF(2, 0), a3 = LDAF(3, 0);
      bf16x8 b0 = LDBF(0, 0), b1 = LDBF(1, 0), b2 = LDBF(2, 0);
      if (t < GM_NT - 1) stageA(nb, k1);
      __builtin_amdgcn_s_setprio(1);
      MROW(0, a0) MROW(1, a1) MROW(2, a2) MROW(3, a3)
      __builtin_amdgcn_s_setprio(0);
    }
    {  // P1: kk1 (12 MFMA) + stage B(t+2) (depth-2)
      bf16x8 a0 = LDAF(0, 1), a1 = LDAF(1, 1), a2 = LDAF(2, 1), a3 = LDAF(3, 1);
      bf16x8 b0 = LDBF(0, 1), b1 = LDBF(1, 1), b2 = LDBF(2, 1);
      if (t < GM_NT - 2 && w < 12) stageB((t + 2) % 3, (t + 2) * 64);
      __builtin_amdgcn_s_setprio(1);
      MROW(0, a0) MROW(1, a1) MROW(2, a2) MROW(3, a3)
      __builtin_amdgcn_s_setprio(0);
    }
  }

#pragma unroll
  for (int mf = 0; mf < 4; ++mf) {
    const int row = m0 + wr * 64 + mf * 16 + g * 4;
#pragma unroll
    for (int nf = 0; nf < 3; ++nf) {
      const int colb = n0 + wc * 48 + nf * 16;
      if (colb >= 2048) {  // V: write transposed to Vt[bh][d][t]
        const int d = colb - 2048 + l15;
        const size_t vo =
            ((size_t)((row >> 11) * 16 + (d >> 6)) * 64 + (d & 63)) * (size_t)T_SZ +
            (row & (T_SZ - 1));
        union { bf16_t h4[4]; uint2 u; } pk;
#pragma unroll
        for (int i = 0; i < 4; ++i) pk.h4[i] = (bf16_t)acc[mf][nf][i];
        *(uint2*)(Vt + vo) = pk.u;
      } else {
#pragma unroll
        for (int i = 0; i < 4; ++i)
          C[(size_t)(row + i) * QKV_LD + colb + l15] = (bf16_t)acc[mf][nf][i];
      }
    }
  }
}

// ---------------- 128x64 dbuf BK=64 GEMM for Wo, f32 out; fully unrolled
__global__ __launch_bounds__(256, 3) void gemm128(
    const bf16_t* __restrict__ A, int lda, const bf16_t* __restrict__ Bt,
    float* __restrict__ C, int N) {
  __shared__ __align__(16) bf16_t As[2][128 * 64];
  __shared__ __align__(16) bf16_t Bs[2][64 * 64];
  const int wg = blockIdx.x + 16 * blockIdx.y;
  const int swz = (wg & 7) * 64 + (wg >> 3);
  const int bx = swz & 15, by = swz >> 4;
  const int m0 = by * 128, n0 = bx * 64;
  const int tid = threadIdx.x, w = tid >> 6, lane = tid & 63;
  const int wr = w >> 1, wc = w & 1;
  const int g = lane >> 4, l15 = lane & 15, sw = l15 & 7;
  const int srow = lane >> 3, sj = lane & 7;

  f32x4 acc[4][2] = {};

  auto stage = [&](int buf, int k0) {
#pragma unroll
    for (int r = 0; r < 4; ++r) {
      const int rg = (w * 4 + r) * 8;
      gload_lds16(A + (size_t)(m0 + rg + srow) * lda + k0 + ((sj ^ srow) << 3),
                  &As[buf][rg * 64]);
    }
#pragma unroll
    for (int r = 0; r < 2; ++r) {
      const int rg = (w * 2 + r) * 8;
      gload_lds16(Bt + (size_t)(n0 + rg + srow) * K_SZ + k0 + ((sj ^ srow) << 3),
                  &Bs[buf][rg * 64]);
    }
  };

  stage(0, 0);

#pragma unroll
  for (int t = 0; t < GM_NT; ++t) {
    const int buf = t & 1;
    asm volatile("s_waitcnt vmcnt(0)" ::: "memory");
    __builtin_amdgcn_s_barrier();
    if (t < GM_NT - 1) stage(buf ^ 1, (t + 1) * 64);
#pragma unroll
    for (int kk = 0; kk < 2; ++kk) {
      bf16x8 af[4], bfr[2];
#pragma unroll
      for (int mf = 0; mf < 4; ++mf)
        af[mf] = *(const bf16x8*)&As[buf][(wr * 64 + mf * 16 + l15) * 64 +
                                          (((kk << 2) | g) ^ sw) * 8];
#pragma unroll
      for (int nf = 0; nf < 2; ++nf)
        bfr[nf] = *(const bf16x8*)&Bs[buf][(wc * 32 + nf * 16 + l15) * 64 +
                                           (((kk << 2) | g) ^ sw) * 8];
      __builtin_amdgcn_s_setprio(1);
#pragma unroll
      for (int mf = 0; mf < 4; ++mf)
#pragma unroll
        for (int nf = 0; nf < 2; ++nf)
          acc[mf][nf] = mfma16(af[mf], bfr[nf], acc[mf][nf]);
      __builtin_amdgcn_s_setprio(0);
    }
    // no end barrier: next entry barrier is the only sync
  }

#pragma unroll
  for (int mf = 0; mf < 4; ++mf)
#pragma unroll
    for (int nf = 0; nf < 2; ++nf)
#pragma unroll
      for (int i = 0; i < 4; ++i)
        C[(size_t)(m0 + wr * 64 + mf * 16 + g * 4 + i) * N +
          n0 + wc * 32 + nf * 16 + l15] = acc[mf][nf][i];
}

// ---------------- flash sliding-window attention, QBLK=128, 8 waves.
// Single barrier per K-tile (stage issued post-barrier, R19 winner).
__global__ __launch_bounds__(512) void attn_kernel(
    bf16_t* __restrict__ QKV, const bf16_t* __restrict__ Vt) {
  __shared__ __align__(16) bf16_t Kl[2][64 * 64];
  __shared__ __align__(16) bf16_t Vl[2][64 * 64];

  const int qt = ((blockIdx.x & 7) << 1) | (blockIdx.x >> 3);
  const int bh = blockIdx.y;
  const int b = bh >> 4, h = bh & 15;
  const int q0 = qt * 128;
  const int tid = threadIdx.x, w = tid >> 6, lane = tid & 63;
  const int g = lane >> 4, l15 = lane & 15, gh = g >> 1;
  const int wrow0 = q0 + w * 16;
  const int myrow = wrow0 + l15;
  const int sub = lane >> 3, jj = lane & 7;
  const int sw = l15 & 7;

  auto stage = [&](int bufi, int kt) {
    const int row = w * 8 + sub;
    const int sj = jj ^ sub;
    gload_lds16(QKV + ((size_t)b * T_SZ + kt + row) * QKV_LD + 1024 + h * D_SZ + sj * 8,
                &Kl[bufi][w * 512]);
    gload_lds16(Vt + ((size_t)bh * D_SZ + row) * T_SZ + kt + sj * 8,
                &Vl[bufi][w * 512]);
  };

  bf16x8 qf[2];
  {
    const bf16_t* qptr = QKV + ((size_t)b * T_SZ + myrow) * QKV_LD + h * D_SZ;
    const float QSC = 0.125f * 1.44269504f;
#pragma unroll
    for (int c2 = 0; c2 < 2; ++c2) {
      bf16x8 t = *(const bf16x8*)(qptr + c2 * 32 + g * 8);
      bf16x8 o;
#pragma unroll
      for (int j = 0; j < 8; ++j) o[j] = (bf16_t)((float)t[j] * QSC);
      qf[c2] = o;
    }
  }

  float m_s = -1e30f, l_s = 0.f;
  f32x4 oacc[4] = {};

  int kstart = q0 - (WIN - 1);
  if (kstart < 0) kstart = 0;
  kstart &= ~63;
  const int nt = (q0 + 128 - kstart) >> 6;

  stage(0, kstart);

  for (int it = 0; it < nt; ++it) {
    const int kt = kstart + (it << 6);
    const int cur = it & 1;
    asm volatile("s_waitcnt vmcnt(0)" ::: "memory");
    __builtin_amdgcn_s_barrier();
    __builtin_amdgcn_sched_barrier(0);
    if (it + 1 < nt) stage(cur ^ 1, kt + 64);

    const bool skip = (kt + 63 < wrow0 - (WIN - 1)) || (kt > wrow0 + 15);
    if (!skip) {
      f32x4 s[4] = {};
#pragma unroll
      for (int t = 0; t < 4; ++t) {
        const bf16_t* kbase = &Kl[cur][(t * 16 + l15) * 64];
#pragma unroll
        for (int c2 = 0; c2 < 2; ++c2) {
          const bf16x8 kf = *(const bf16x8*)(kbase + (((c2 * 4 + g) ^ sw) << 3));
          s[t] = mfma16(kf, qf[c2], s[t]);
        }
      }

      const bool interior = (kt + 63 <= wrow0) && (kt >= wrow0 + 15 - (WIN - 1));
      float sv[4][4];
      if (interior) {
#pragma unroll
        for (int t = 0; t < 4; ++t)
#pragma unroll
          for (int i = 0; i < 4; ++i) sv[t][i] = s[t][i];
      } else {
#pragma unroll
        for (int t = 0; t < 4; ++t)
#pragma unroll
          for (int i = 0; i < 4; ++i) {
            const int kk = kt + t * 16 + g * 4 + i;
            sv[t][i] = (kk <= myrow && kk > myrow - WIN) ? s[t][i] : -1e30f;
          }
      }

      float mx = sv[0][0];
#pragma unroll
      for (int t = 0; t < 4; ++t)
#pragma unroll
        for (int i = 0; i < 4; ++i)
          if (t || i) mx = fmaxf(mx, sv[t][i]);
      mx = fmaxf(mx, __shfl_xor(mx, 16));
      mx = fmaxf(mx, __shfl_xor(mx, 32));

      float mbase;
      const bool defer = __all((mx <= m_s + 8.f) && (m_s > -1e29f));
      if (defer) {
        mbase = m_s;
      } else {
        const float mnew = fmaxf(m_s, mx);
        const float scl = exp2f(m_s - mnew);
        m_s = mnew;
        mbase = (mnew > -1e29f) ? mnew : 1e30f;
        float sc4[4];
#pragma unroll
        for (int i = 0; i < 4; ++i) sc4[i] = __shfl(scl, g * 4 + i, 16);
#pragma unroll
        for (int c = 0; c < 4; ++c)
#pragma unroll
          for (int i = 0; i < 4; ++i) oacc[c][i] *= sc4[i];
        l_s *= scl;
      }

      float p[4][4];
      float rsum = 0.f;
#pragma unroll
      for (int t = 0; t < 4; ++t)
#pragma unroll
        for (int i = 0; i < 4; ++i) {
          p[t][i] = exp2f(sv[t][i] - mbase);
          rsum += p[t][i];
        }
      rsum += __shfl_xor(rsum, 16);
      rsum += __shfl_xor(rsum, 32);
      l_s += rsum;

      u32 Wp[4][2];
#pragma unroll
      for (int t = 0; t < 4; ++t)
#pragma unroll
        for (int w2 = 0; w2 < 2; ++w2) {
          union { bf16_t hh[2]; u32 uu; } pk;
          pk.hh[0] = (bf16_t)p[t][2 * w2];
          pk.hh[1] = (bf16_t)p[t][2 * w2 + 1];
          Wp[t][w2] = pk.uu;
        }

#pragma unroll
      for (int kp = 0; kp < 2; ++kp) {
        const u32 lo0 = Wp[2 * kp][0], lo1 = Wp[2 * kp][1];
        const u32 hi0 = Wp[2 * kp + 1][0], hi1 = Wp[2 * kp + 1][1];
        union { u32 u[4]; bf16x8 v; } pa;
        pa.u[0] = gh ? hi0 : lo0;
        pa.u[1] = gh ? hi1 : lo1;
        pa.u[2] = (u32)__shfl_xor((int)(gh ? lo0 : hi0), 32);
        pa.u[3] = (u32)__shfl_xor((int)(gh ? lo1 : hi1), 32);

        const int tA = 2 * kp + gh;
        const int low = (g & 1) * 4;
        const int cA = ((tA * 2 + gh) ^ sw) << 3;
        const int cB = ((tA * 2 + (gh ^ 1)) ^ sw) << 3;
#pragma unroll
        for (int c = 0; c < 4; ++c) {
          const bf16_t* vbase = &Vl[cur][(c * 16 + l15) * 64];
          union { bf16x4 h[2]; bf16x8 v; } vv;
          vv.h[0] = *(const bf16x4*)(vbase + cA + low);
          vv.h[1] = *(const bf16x4*)(vbase + cB + low);
          oacc[c] = mfma16(pa.v, vv.v, oacc[c]);
        }
      }
    }
    __builtin_amdgcn_sched_barrier(0);
  }

  const float invl = 1.0f / l_s;
  float inv4[4];
#pragma unroll
  for (int i = 0; i < 4; ++i) inv4[i] = __shfl(invl, g * 4 + i, 16);
#pragma unroll
  for (int i = 0; i < 4; ++i) {
    const size_t ro = ((size_t)b * T_SZ + wrow0 + g * 4 + i) * QKV_LD + 2048 + h * D_SZ;
#pragma unroll
    for (int c = 0; c < 4; ++c)
      QKV[ro + c * 16 + l15] = (bf16_t)(oacc[c][i] * inv4[i]);
  }
}

extern "C" void kernel_launch(void* const* d_in, const int* in_sizes, int n_in,
                              void* d_out, int out_size, void* d_ws, size_t ws_size,
                              hipStream_t stream) {
  const float* x = (const float*)d_in[0];
  const float* Wq = (const float*)d_in[1];
  const float* Wk = (const float*)d_in[2];
  const float* Wv = (const float*)d_in[3];
  const float* Wo = (const float*)d_in[4];
  float* out = (float*)d_out;
  char* ws = (char*)d_ws;
  const size_t MB = 1ull << 20;
  bf16_t* xb = (bf16_t*)(ws);                // [4096][1024] bf16 x
  bf16_t* QKVb = (bf16_t*)(ws + 8 * MB);     // [4096][3072]; V-cols hold attn out
  bf16_t* WqT = (bf16_t*)(ws + 32 * MB);     // [3072][1024] combined (q|k|v)
  bf16_t* WkT = (bf16_t*)(ws + 34 * MB);
  bf16_t* WvT = (bf16_t*)(ws + 36 * MB);
  bf16_t* WoT = (bf16_t*)(ws + 38 * MB);
  bf16_t* Vtp = (bf16_t*)(ws + 48 * MB);     // Vt [32][64][2048]

  prep<<<dim3(32, 32, 5), 256, 0, stream>>>(x, xb, Wq, Wk, Wv, Wo,
                                            WqT, WkT, WvT, WoT);
  gemm256<<<dim3(16, 16), 1024, 0, stream>>>(xb, WqT, QKVb, Vtp);
  attn_kernel<<<dim3(16, B_SZ * H_CNT), 512, 0, stream>>>(QKVb, Vtp);
  gemm128<<<dim3(16, 32), 256, 0, stream>>>(QKVb + 2048, QKV_LD, WoT, out, C_SZ);
}

// Round 21
// 81.733 us; speedup vs baseline: 1.0053x; 1.0053x over previous
//
#include <hip/hip_runtime.h>

#define B_SZ 2
#define T_SZ 2048
#define C_SZ 1024
#define K_SZ 1024
#define QKV_LD 3072
#define H_CNT 16
#define D_SZ 64
#define WIN 512

typedef __bf16 bf16_t;
typedef bf16_t bf16x8 __attribute__((ext_vector_type(8)));
typedef bf16_t bf16x4 __attribute__((ext_vector_type(4)));
typedef float f32x4 __attribute__((ext_vector_type(4)));
typedef unsigned int u32;

__device__ __forceinline__ f32x4 mfma16(bf16x8 a, bf16x8 b, f32x4 c) {
  return __builtin_amdgcn_mfma_f32_16x16x32_bf16(a, b, c, 0, 0, 0);
}

__device__ __forceinline__ void gload_lds16(const void* gsrc, void* ldst) {
  auto g = (__attribute__((address_space(1))) void*)(unsigned long long)gsrc;
  auto l = (__attribute__((address_space(3))) void*)(unsigned int)(unsigned long long)ldst;
  __builtin_amdgcn_global_load_lds(g, l, 16, 0, 0);
}

// ---------------- prep: weight transpose+convert (z<4) | x convert (z==4)
__global__ __launch_bounds__(256) void prep(
    const float* __restrict__ x, bf16_t* __restrict__ xb,
    const float* __restrict__ W0, const float* __restrict__ W1,
    const float* __restrict__ W2, const float* __restrict__ W3,
    bf16_t* __restrict__ T0, bf16_t* __restrict__ T1,
    bf16_t* __restrict__ T2, bf16_t* __restrict__ T3) {
  if (blockIdx.z == 4) {
    const int base = (blockIdx.y * 32 + blockIdx.x) * 256 + threadIdx.x;
#pragma unroll
    for (int j = 0; j < 4; ++j) {
      const int idx = base + j * 262144;
      const float4 v = ((const float4*)x)[idx];
      bf16x4 r;
      r[0] = (bf16_t)v.x; r[1] = (bf16_t)v.y; r[2] = (bf16_t)v.z; r[3] = (bf16_t)v.w;
      ((bf16x4*)xb)[idx] = r;
    }
    return;
  }
  __shared__ float tile[32][33];
  const float* W = blockIdx.z == 0 ? W0 : blockIdx.z == 1 ? W1 : blockIdx.z == 2 ? W2 : W3;
  bf16_t* Tt = blockIdx.z == 0 ? T0 : blockIdx.z == 1 ? T1 : blockIdx.z == 2 ? T2 : T3;
  const int tx = threadIdx.x & 31, ty = threadIdx.x >> 5;
  const int r0 = blockIdx.y * 32, c0 = blockIdx.x * 32;
#pragma unroll
  for (int i = 0; i < 4; ++i)
    tile[ty + i * 8][tx] = W[(size_t)(r0 + ty + i * 8) * C_SZ + c0 + tx];
  __syncthreads();
#pragma unroll
  for (int i = 0; i < 4; ++i)
    Tt[(size_t)(c0 + ty + i * 8) * C_SZ + r0 + tx] = (bf16_t)tile[tx][ty + i * 8];
}

// ---------------- 256x192 GEMM, BK=64, 8 waves 4Mx2N, single entry barrier.
// A double-buffered (depth-1, L2-hot), B triple-buffered (depth-2, HBM);
// entry vmcnt(3) leaves B(t+1) in flight. K-loop fully unrolled.
#define GM_NT 16  // K / 64

__global__ __launch_bounds__(512, 2) void gemm256(
    const bf16_t* __restrict__ A, const bf16_t* __restrict__ Bt,
    bf16_t* __restrict__ C, bf16_t* __restrict__ Vt) {
  __shared__ __align__(16) bf16_t As[2][256 * 64];
  __shared__ __align__(16) bf16_t Bs[3][192 * 64];
  const int wg = blockIdx.x + 16 * blockIdx.y;
  const int swz = (wg & 7) * 32 + (wg >> 3);
  const int bx = swz & 15, by = swz >> 4;
  const int m0 = by * 256, n0 = bx * 192;
  const int tid = threadIdx.x, w = tid >> 6, lane = tid & 63;
  const int wr = w >> 1, wc = w & 1;  // 4M x 2N
  const int g = lane >> 4, l15 = lane & 15, sw = l15 & 7;
  const int srow = lane >> 3, sj = lane & 7;

  f32x4 acc[4][6] = {};

  auto stageA = [&](int buf, int half, int k0) {
#pragma unroll
    for (int q8 = 0; q8 < 2; ++q8) {
      const int rg = w * 16 + q8 * 8;
      gload_lds16(A + (size_t)(m0 + half * 128 + rg + srow) * K_SZ + k0 + ((sj ^ srow) << 3),
                  &As[buf][half * 8192 + rg * 64]);
    }
  };
  auto stageB = [&](int buf, int third, int k0) {
    const int rg = third * 64 + w * 8;
    gload_lds16(Bt + (size_t)(n0 + rg + srow) * K_SZ + k0 + ((sj ^ srow) << 3),
                &Bs[buf][rg * 64]);
  };

  stageB(0, 0, 0); stageB(0, 1, 0); stageB(0, 2, 0);
  stageA(0, 0, 0); stageA(0, 1, 0);
  stageB(1, 0, 64); stageB(1, 1, 64); stageB(1, 2, 64);

#define LDAF(MF, KK) \
  (*(const bf16x8*)&As[buf][(wr * 64 + (MF) * 16 + l15) * 64 + \
                            ((((KK) << 2) | g) ^ sw) * 8])
#define LDBF(NF, KK) \
  (*(const bf16x8*)&Bs[bB][(wc * 96 + (NF) * 16 + l15) * 64 + \
                           ((((KK) << 2) | g) ^ sw) * 8])
#define MROW(MF, AF)                              \
  acc[(MF)][0] = mfma16(AF, b0, acc[(MF)][0]);    \
  acc[(MF)][1] = mfma16(AF, b1, acc[(MF)][1]);    \
  acc[(MF)][2] = mfma16(AF, b2, acc[(MF)][2]);    \
  acc[(MF)][3] = mfma16(AF, b3, acc[(MF)][3]);    \
  acc[(MF)][4] = mfma16(AF, b4, acc[(MF)][4]);    \
  acc[(MF)][5] = mfma16(AF, b5, acc[(MF)][5]);

#pragma unroll
  for (int t = 0; t < GM_NT; ++t) {
    const int buf = t & 1, nb = buf ^ 1;
    const int bB = t % 3;  // compile-time after full unroll
    const int k1 = (t + 1) * 64;
    if (t < GM_NT - 1) {
      asm volatile("s_waitcnt vmcnt(3)" ::: "memory");
    } else {
      asm volatile("s_waitcnt vmcnt(0)" ::: "memory");
    }
    __builtin_amdgcn_s_barrier();

    {  // P0: kk0 (24 MFMA) + stage A(t+1)
      bf16x8 a0 = LDAF(0, 0), a1 = LDAF(1, 0), a2 = LDAF(2, 0), a3 = LDAF(3, 0);
      bf16x8 b0 = LDBF(0, 0), b1 = LDBF(1, 0), b2 = LDBF(2, 0),
             b3 = LDBF(3, 0), b4 = LDBF(4, 0), b5 = LDBF(5, 0);
      if (t < GM_NT - 1) { stageA(nb, 0, k1); stageA(nb, 1, k1); }
      __builtin_amdgcn_s_setprio(1);
      MROW(0, a0) MROW(1, a1) MROW(2, a2) MROW(3, a3)
      __builtin_amdgcn_s_setprio(0);
    }
    {  // P1: kk1 (24 MFMA) + stage B(t+2) (depth-2)
      bf16x8 a0 = LDAF(0, 1), a1 = LDAF(1, 1), a2 = LDAF(2, 1), a3 = LDAF(3, 1);
      bf16x8 b0 = LDBF(0, 1), b1 = LDBF(1, 1), b2 = LDBF(2, 1),
             b3 = LDBF(3, 1), b4 = LDBF(4, 1), b5 = LDBF(5, 1);
      if (t < GM_NT - 2) {
        const int b2s = (t + 2) % 3;
        const int k2 = (t + 2) * 64;
        stageB(b2s, 0, k2); stageB(b2s, 1, k2); stageB(b2s, 2, k2);
      }
      __builtin_amdgcn_s_setprio(1);
      MROW(0, a0) MROW(1, a1) MROW(2, a2) MROW(3, a3)
      __builtin_amdgcn_s_setprio(0);
    }
  }

#pragma unroll
  for (int mf = 0; mf < 4; ++mf) {
    const int row = m0 + wr * 64 + mf * 16 + g * 4;
#pragma unroll
    for (int nf = 0; nf < 6; ++nf) {
      const int colb = n0 + wc * 96 + nf * 16;
      if (colb >= 2048) {  // V: write transposed to Vt[bh][d][t]
        const int d = colb - 2048 + l15;
        const size_t vo =
            ((size_t)((row >> 11) * 16 + (d >> 6)) * 64 + (d & 63)) * (size_t)T_SZ +
            (row & (T_SZ - 1));
        union { bf16_t h4[4]; uint2 u; } pk;
#pragma unroll
        for (int i = 0; i < 4; ++i) pk.h4[i] = (bf16_t)acc[mf][nf][i];
        *(uint2*)(Vt + vo) = pk.u;
      } else {
#pragma unroll
        for (int i = 0; i < 4; ++i)
          C[(size_t)(row + i) * QKV_LD + colb + l15] = (bf16_t)acc[mf][nf][i];
      }
    }
  }
}

// ---------------- 128x64 dbuf BK=64 GEMM for Wo, f32 out; fully unrolled
__global__ __launch_bounds__(256, 3) void gemm128(
    const bf16_t* __restrict__ A, int lda, const bf16_t* __restrict__ Bt,
    float* __restrict__ C, int N) {
  __shared__ __align__(16) bf16_t As[2][128 * 64];
  __shared__ __align__(16) bf16_t Bs[2][64 * 64];
  const int wg = blockIdx.x + 16 * blockIdx.y;
  const int swz = (wg & 7) * 64 + (wg >> 3);
  const int bx = swz & 15, by = swz >> 4;
  const int m0 = by * 128, n0 = bx * 64;
  const int tid = threadIdx.x, w = tid >> 6, lane = tid & 63;
  const int wr = w >> 1, wc = w & 1;
  const int g = lane >> 4, l15 = lane & 15, sw = l15 & 7;
  const int srow = lane >> 3, sj = lane & 7;

  f32x4 acc[4][2] = {};

  auto stage = [&](int buf, int k0) {
#pragma unroll
    for (int r = 0; r < 4; ++r) {
      const int rg = (w * 4 + r) * 8;
      gload_lds16(A + (size_t)(m0 + rg + srow) * lda + k0 + ((sj ^ srow) << 3),
                  &As[buf][rg * 64]);
    }
#pragma unroll
    for (int r = 0; r < 2; ++r) {
      const int rg = (w * 2 + r) * 8;
      gload_lds16(Bt + (size_t)(n0 + rg + srow) * K_SZ + k0 + ((sj ^ srow) << 3),
                  &Bs[buf][rg * 64]);
    }
  };

  stage(0, 0);

#pragma unroll
  for (int t = 0; t < GM_NT; ++t) {
    const int buf = t & 1;
    asm volatile("s_waitcnt vmcnt(0)" ::: "memory");
    __builtin_amdgcn_s_barrier();
    if (t < GM_NT - 1) stage(buf ^ 1, (t + 1) * 64);
#pragma unroll
    for (int kk = 0; kk < 2; ++kk) {
      bf16x8 af[4], bfr[2];
#pragma unroll
      for (int mf = 0; mf < 4; ++mf)
        af[mf] = *(const bf16x8*)&As[buf][(wr * 64 + mf * 16 + l15) * 64 +
                                          (((kk << 2) | g) ^ sw) * 8];
#pragma unroll
      for (int nf = 0; nf < 2; ++nf)
        bfr[nf] = *(const bf16x8*)&Bs[buf][(wc * 32 + nf * 16 + l15) * 64 +
                                           (((kk << 2) | g) ^ sw) * 8];
      __builtin_amdgcn_s_setprio(1);
#pragma unroll
      for (int mf = 0; mf < 4; ++mf)
#pragma unroll
        for (int nf = 0; nf < 2; ++nf)
          acc[mf][nf] = mfma16(af[mf], bfr[nf], acc[mf][nf]);
      __builtin_amdgcn_s_setprio(0);
    }
    // no end barrier: next entry barrier is the only sync
  }

#pragma unroll
  for (int mf = 0; mf < 4; ++mf)
#pragma unroll
    for (int nf = 0; nf < 2; ++nf)
#pragma unroll
      for (int i = 0; i < 4; ++i)
        C[(size_t)(m0 + wr * 64 + mf * 16 + g * 4 + i) * N +
          n0 + wc * 32 + nf * 16 + l15] = acc[mf][nf][i];
}

// ---------------- flash sliding-window attention, QBLK=128, 8 waves.
// Single barrier per K-tile (stage issued post-barrier).
__global__ __launch_bounds__(512) void attn_kernel(
    bf16_t* __restrict__ QKV, const bf16_t* __restrict__ Vt) {
  __shared__ __align__(16) bf16_t Kl[2][64 * 64];
  __shared__ __align__(16) bf16_t Vl[2][64 * 64];

  const int qt = ((blockIdx.x & 7) << 1) | (blockIdx.x >> 3);
  const int bh = blockIdx.y;
  const int b = bh >> 4, h = bh & 15;
  const int q0 = qt * 128;
  const int tid = threadIdx.x, w = tid >> 6, lane = tid & 63;
  const int g = lane >> 4, l15 = lane & 15, gh = g >> 1;
  const int wrow0 = q0 + w * 16;
  const int myrow = wrow0 + l15;
  const int sub = lane >> 3, jj = lane & 7;
  const int sw = l15 & 7;

  auto stage = [&](int bufi, int kt) {
    const int row = w * 8 + sub;
    const int sj = jj ^ sub;
    gload_lds16(QKV + ((size_t)b * T_SZ + kt + row) * QKV_LD + 1024 + h * D_SZ + sj * 8,
                &Kl[bufi][w * 512]);
    gload_lds16(Vt + ((size_t)bh * D_SZ + row) * T_SZ + kt + sj * 8,
                &Vl[bufi][w * 512]);
  };

  bf16x8 qf[2];
  {
    const bf16_t* qptr = QKV + ((size_t)b * T_SZ + myrow) * QKV_LD + h * D_SZ;
    const float QSC = 0.125f * 1.44269504f;
#pragma unroll
    for (int c2 = 0; c2 < 2; ++c2) {
      bf16x8 t = *(const bf16x8*)(qptr + c2 * 32 + g * 8);
      bf16x8 o;
#pragma unroll
      for (int j = 0; j < 8; ++j) o[j] = (bf16_t)((float)t[j] * QSC);
      qf[c2] = o;
    }
  }

  float m_s = -1e30f, l_s = 0.f;
  f32x4 oacc[4] = {};

  int kstart = q0 - (WIN - 1);
  if (kstart < 0) kstart = 0;
  kstart &= ~63;
  const int nt = (q0 + 128 - kstart) >> 6;

  stage(0, kstart);

  for (int it = 0; it < nt; ++it) {
    const int kt = kstart + (it << 6);
    const int cur = it & 1;
    asm volatile("s_waitcnt vmcnt(0)" ::: "memory");
    __builtin_amdgcn_s_barrier();
    __builtin_amdgcn_sched_barrier(0);
    if (it + 1 < nt) stage(cur ^ 1, kt + 64);

    const bool skip = (kt + 63 < wrow0 - (WIN - 1)) || (kt > wrow0 + 15);
    if (!skip) {
      f32x4 s[4] = {};
#pragma unroll
      for (int t = 0; t < 4; ++t) {
        const bf16_t* kbase = &Kl[cur][(t * 16 + l15) * 64];
#pragma unroll
        for (int c2 = 0; c2 < 2; ++c2) {
          const bf16x8 kf = *(const bf16x8*)(kbase + (((c2 * 4 + g) ^ sw) << 3));
          s[t] = mfma16(kf, qf[c2], s[t]);
        }
      }

      const bool interior = (kt + 63 <= wrow0) && (kt >= wrow0 + 15 - (WIN - 1));
      float sv[4][4];
      if (interior) {
#pragma unroll
        for (int t = 0; t < 4; ++t)
#pragma unroll
          for (int i = 0; i < 4; ++i) sv[t][i] = s[t][i];
      } else {
#pragma unroll
        for (int t = 0; t < 4; ++t)
#pragma unroll
          for (int i = 0; i < 4; ++i) {
            const int kk = kt + t * 16 + g * 4 + i;
            sv[t][i] = (kk <= myrow && kk > myrow - WIN) ? s[t][i] : -1e30f;
          }
      }

      float mx = sv[0][0];
#pragma unroll
      for (int t = 0; t < 4; ++t)
#pragma unroll
        for (int i = 0; i < 4; ++i)
          if (t || i) mx = fmaxf(mx, sv[t][i]);
      mx = fmaxf(mx, __shfl_xor(mx, 16));
      mx = fmaxf(mx, __shfl_xor(mx, 32));

      float mbase;
      const bool defer = __all((mx <= m_s + 8.f) && (m_s > -1e29f));
      if (defer) {
        mbase = m_s;
      } else {
        const float mnew = fmaxf(m_s, mx);
        const float scl = exp2f(m_s - mnew);
        m_s = mnew;
        mbase = (mnew > -1e29f) ? mnew : 1e30f;
        float sc4[4];
#pragma unroll
        for (int i = 0; i < 4; ++i) sc4[i] = __shfl(scl, g * 4 + i, 16);
#pragma unroll
        for (int c = 0; c < 4; ++c)
#pragma unroll
          for (int i = 0; i < 4; ++i) oacc[c][i] *= sc4[i];
        l_s *= scl;
      }

      float p[4][4];
      float rsum = 0.f;
#pragma unroll
      for (int t = 0; t < 4; ++t)
#pragma unroll
        for (int i = 0; i < 4; ++i) {
          p[t][i] = exp2f(sv[t][i] - mbase);
          rsum += p[t][i];
        }
      rsum += __shfl_xor(rsum, 16);
      rsum += __shfl_xor(rsum, 32);
      l_s += rsum;

      u32 Wp[4][2];
#pragma unroll
      for (int t = 0; t < 4; ++t)
#pragma unroll
        for (int w2 = 0; w2 < 2; ++w2) {
          union { bf16_t hh[2]; u32 uu; } pk;
          pk.hh[0] = (bf16_t)p[t][2 * w2];
          pk.hh[1] = (bf16_t)p[t][2 * w2 + 1];
          Wp[t][w2] = pk.uu;
        }

#pragma unroll
      for (int kp = 0; kp < 2; ++kp) {
        const u32 lo0 = Wp[2 * kp][0], lo1 = Wp[2 * kp][1];
        const u32 hi0 = Wp[2 * kp + 1][0], hi1 = Wp[2 * kp + 1][1];
        union { u32 u[4]; bf16x8 v; } pa;
        pa.u[0] = gh ? hi0 : lo0;
        pa.u[1] = gh ? hi1 : lo1;
        pa.u[2] = (u32)__shfl_xor((int)(gh ? lo0 : hi0), 32);
        pa.u[3] = (u32)__shfl_xor((int)(gh ? lo1 : hi1), 32);

        const int tA = 2 * kp + gh;
        const int low = (g & 1) * 4;
        const int cA = ((tA * 2 + gh) ^ sw) << 3;
        const int cB = ((tA * 2 + (gh ^ 1)) ^ sw) << 3;
#pragma unroll
        for (int c = 0; c < 4; ++c) {
          const bf16_t* vbase = &Vl[cur][(c * 16 + l15) * 64];
          union { bf16x4 h[2]; bf16x8 v; } vv;
          vv.h[0] = *(const bf16x4*)(vbase + cA + low);
          vv.h[1] = *(const bf16x4*)(vbase + cB + low);
          oacc[c] = mfma16(pa.v, vv.v, oacc[c]);
        }
      }
    }
    __builtin_amdgcn_sched_barrier(0);
  }

  const float invl = 1.0f / l_s;
  float inv4[4];
#pragma unroll
  for (int i = 0; i < 4; ++i) inv4[i] = __shfl(invl, g * 4 + i, 16);
#pragma unroll
  for (int i = 0; i < 4; ++i) {
    const size_t ro = ((size_t)b * T_SZ + wrow0 + g * 4 + i) * QKV_LD + 2048 + h * D_SZ;
#pragma unroll
    for (int c = 0; c < 4; ++c)
      QKV[ro + c * 16 + l15] = (bf16_t)(oacc[c][i] * inv4[i]);
  }
}

extern "C" void kernel_launch(void* const* d_in, const int* in_sizes, int n_in,
                              void* d_out, int out_size, void* d_ws, size_t ws_size,
                              hipStream_t stream) {
  const float* x = (const float*)d_in[0];
  const float* Wq = (const float*)d_in[1];
  const float* Wk = (const float*)d_in[2];
  const float* Wv = (const float*)d_in[3];
  const float* Wo = (const float*)d_in[4];
  float* out = (float*)d_out;
  char* ws = (char*)d_ws;
  const size_t MB = 1ull << 20;
  bf16_t* xb = (bf16_t*)(ws);                // [4096][1024] bf16 x
  bf16_t* QKVb = (bf16_t*)(ws + 8 * MB);     // [4096][3072]; V-cols hold attn out
  bf16_t* WqT = (bf16_t*)(ws + 32 * MB);     // [3072][1024] combined (q|k|v)
  bf16_t* WkT = (bf16_t*)(ws + 34 * MB);
  bf16_t* WvT = (bf16_t*)(ws + 36 * MB);
  bf16_t* WoT = (bf16_t*)(ws + 38 * MB);
  bf16_t* Vtp = (bf16_t*)(ws + 48 * MB);     // Vt [32][64][2048]

  prep<<<dim3(32, 32, 5), 256, 0, stream>>>(x, xb, Wq, Wk, Wv, Wo,
                                            WqT, WkT, WvT, WoT);
  gemm256<<<dim3(16, 16), 512, 0, stream>>>(xb, WqT, QKVb, Vtp);
  attn_kernel<<<dim3(16, B_SZ * H_CNT), 512, 0, stream>>>(QKVb, Vtp);
  gemm128<<<dim3(16, 32), 256, 0, stream>>>(QKVb + 2048, QKV_LD, WoT, out, C_SZ);
}